// Round 12
// baseline (350.563 us; speedup 1.0000x reference)
//
#include <hip/hip_runtime.h>
#include <hip/hip_bf16.h>
#include <stdint.h>

#define S_LEN 2048
#define B_SZ  16
#define D_DIM 1024
#define H_DIM 1024
#define M_TOT (S_LEN * B_SZ)      // 32768
#define N_TOT (3 * H_DIM)         // 3072
#define K_TOT D_DIM               // 1024

// ---- GEMM geometry: 256x256 tile, BK=64, 4 waves (2x2, 128x128 each) ----
#define BM 256
#define BN 256
#define BK 64
#define NT   (K_TOT / BK)         // 16 K-tiles
#define NTN  (N_TOT / BN)         // 12
#define NWG  ((M_TOT / BM) * NTN) // 1536 (divisible by 8 -> simple XCD swizzle)

#define NCHUNK 32
#define CLEN   64                 // NCHUNK*CLEN == S_LEN
#define NCH    (B_SZ * H_DIM)     // 16384 independent channels

typedef __attribute__((ext_vector_type(8))) short short8;
typedef __attribute__((ext_vector_type(4))) float f32x4;

// ---------- helpers ----------
__device__ __forceinline__ void gload_lds16(const void* g, void* l) {
  __builtin_amdgcn_global_load_lds((__attribute__((address_space(1))) void*)g,
                                   (__attribute__((address_space(3))) void*)l,
                                   16, 0, 0);
}

__device__ __forceinline__ unsigned short f2bfbits(float x) {
  union { __hip_bfloat16 h; unsigned short u; } cv;
  cv.h = __float2bfloat16(x);
  return cv.u;
}

// cheap native sigmoid/tanh (v_exp + v_rcp)
__device__ __forceinline__ float sig_fast(float y) {
  float e = __expf(y);
  return e * __builtin_amdgcn_rcpf(1.f + e);
}
__device__ __forceinline__ float tanh_fast(float y) {
  float e = __expf(2.f * y);
  return 2.f * (e * __builtin_amdgcn_rcpf(1.f + e)) - 1.f;
}

// ---------- fp32 -> bf16 conversion (vectorized) ----------
__global__ void cvt_kernel(const float* __restrict__ in,
                           unsigned short* __restrict__ out, int n4) {
  int i = blockIdx.x * 256 + threadIdx.x;
  if (i < n4) {
    float4 v = ((const float4*)in)[i];
    ushort4 o;
    o.x = f2bfbits(v.x); o.y = f2bfbits(v.y);
    o.z = f2bfbits(v.z); o.w = f2bfbits(v.w);
    ((ushort4*)out)[i] = o;
  }
}

// ---------- GEMM: Y = Xb * Wb^T + bias -> raw bf16 Y chunks ----------
// 4 waves, 128x128 register tile each (acc 256 VGPR): LDS reads per K-tile
// drop 192KB -> 128KB (waves x (wM+wN) x BK x 2B), making the kernel
// MFMA-bound (512 < 620 cyc). 1 wave/SIMD; R9 rotation schedule retained:
// 4 quadrant phases/tile, 1 half staged per phase (4 gloads), counted
// vmcnt(12) steady (3 halves in flight), tails 8/4/0.
// LDS: A [2 buf][256 rows][128 B] @0, B same @65536 (128 KiB).
// slot^(row&7) involution swizzle (pre-swizzled global source + read-side).
// A and B halves BOTH bit6-aligned (wave spans 128 rows/cols).
__global__ __launch_bounds__(256, 1) void gemm_act(
    const __hip_bfloat16* __restrict__ Xb,
    const __hip_bfloat16* __restrict__ Wb,
    const float* __restrict__ bias,
    unsigned short* __restrict__ wsZ,
    unsigned short* __restrict__ wsF,
    unsigned short* __restrict__ wsO) {
  __shared__ __align__(16) char lds[131072];

  int bid = blockIdx.x;
  int swz = (bid & 7) * (NWG >> 3) + (bid >> 3);   // XCD-aware, bijective
  int tm  = swz / NTN;
  int tn  = swz - tm * NTN;
  const int m0 = tm * BM;
  const int n0 = tn * BN;

  const int tid  = threadIdx.x;
  const int lane = tid & 63;
  const int wid  = tid >> 6;
  const int wr   = wid >> 1;        // 0..1 : wave row (128 rows)
  const int wc   = wid & 1;         // 0..1 : wave col (128 cols)
  const int lr   = lane & 15;
  const int lg   = lane >> 4;

  const char* Ab = (const char*)(Xb + (size_t)m0 * K_TOT);
  const char* Bb = (const char*)(Wb + (size_t)n0 * K_TOT);

  f32x4 acc[8][8];                  // 256 VGPR accumulator
  const f32x4 vz = {0.f, 0.f, 0.f, 0.f};
  #pragma unroll
  for (int m = 0; m < 8; ++m)
    #pragma unroll
    for (int n = 0; n < 8; ++n) acc[m][n] = vz;

  // stage one bit6-aligned half (128 rows) of one matrix: 4 gloads/thread
  #define STAGE(gb, loff, tt, h)                                              \
    {                                                                         \
      char* l = lds + (loff) + (((tt) & 1) << 15);                            \
      int u = tid >> 3;                                                       \
      _Pragma("unroll")                                                       \
      for (int j = 0; j < 4; ++j) {                                           \
        int r = ((j & 1) << 7) + (h) * 64 + ((j >> 1) << 5) + u;              \
        gload_lds16((gb) + (size_t)r * (K_TOT * 2) + (size_t)(tt) * (BK * 2)  \
                        + (((tid & 7) ^ (r & 7)) << 4),                       \
                    l + r * 128 + ((tid & 7) << 4));                          \
      }                                                                       \
    }

  #define BAR()                                                               \
    { asm volatile("" ::: "memory");                                          \
      __builtin_amdgcn_s_barrier();                                           \
      asm volatile("" ::: "memory"); }

  #define LGKM0()                                                             \
    { asm volatile("s_waitcnt lgkmcnt(0)" ::: "memory");                      \
      __builtin_amdgcn_sched_barrier(0); }

  #define VMC(n)                                                              \
    { asm volatile("s_waitcnt vmcnt(" #n ")" ::: "memory");                   \
      __builtin_amdgcn_sched_barrier(0); }

  // read A quadrant: 8 frags (4 mm x 2 ks); rows bit6 == mh
  #define READ_A(dst, tb, mh)                                                 \
    _Pragma("unroll")                                                         \
    for (int mm = 0; mm < 4; ++mm)                                            \
      _Pragma("unroll")                                                       \
      for (int ks = 0; ks < 2; ++ks) {                                        \
        int row = wr * 128 + (mh) * 64 + mm * 16 + lr;                        \
        dst[mm][ks] = *(const short8*)(lds + ((tb) << 15) + row * 128 +       \
                                       ((((ks << 2) | lg) ^ (row & 7)) << 4));\
      }

  // read B quadrant: 8 frags (4 nn x 2 ks); rows bit6 == nh
  #define READ_B(dst, tb, nh)                                                 \
    _Pragma("unroll")                                                         \
    for (int nn = 0; nn < 4; ++nn)                                            \
      _Pragma("unroll")                                                       \
      for (int ks = 0; ks < 2; ++ks) {                                        \
        int row = wc * 128 + (nh) * 64 + nn * 16 + lr;                        \
        dst[nn][ks] = *(const short8*)(lds + 65536 + ((tb) << 15) +           \
                                       row * 128 +                            \
                                       ((((ks << 2) | lg) ^ (row & 7)) << 4));\
      }

  // quadrant (mh,nh): 4mm x 4nn x 2ks = 32 MFMA
  #define MFMA_Q(mh, nh, A, Bf)                                               \
    __builtin_amdgcn_s_setprio(1);                                            \
    _Pragma("unroll")                                                         \
    for (int ks = 0; ks < 2; ++ks)                                            \
      _Pragma("unroll")                                                       \
      for (int mm = 0; mm < 4; ++mm)                                          \
        _Pragma("unroll")                                                     \
        for (int nn = 0; nn < 4; ++nn)                                        \
          acc[(mh) * 4 + mm][(nh) * 4 + nn] =                                 \
              __builtin_amdgcn_mfma_f32_16x16x32_bf16(                        \
                  A[mm][ks], Bf[nn][ks], acc[(mh) * 4 + mm][(nh) * 4 + nn],   \
                  0, 0, 0);                                                   \
    __builtin_amdgcn_s_setprio(0);

  // prologue: certify {Ah0(0),Bh0(0)}; in-flight {Bh1(0),Ah1(0),Bh0(1)} = 12
  STAGE(Ab, 0, 0, 0);
  STAGE(Bb, 65536, 0, 0);
  STAGE(Bb, 65536, 0, 1);
  STAGE(Ab, 0, 0, 1);
  STAGE(Bb, 65536, 1, 0);
  VMC(12);
  BAR();

  short8 afr[4][2], bfr0[4][2], bfr1[4][2];
  READ_B(bfr0, 0, 0);   // carry-read Bh0(0) (certified)

  for (int t = 0; t < NT; ++t) {
    const int tb = t & 1;
    // ---- q0: read A(mh0); stage Ah0(t+1); certify Bh1(t) ----
    READ_A(afr, tb, 0);
    if (t + 1 < NT) { STAGE(Ab, 0, t + 1, 0); VMC(12); } else { VMC(4); }
    BAR();
    LGKM0();
    MFMA_Q(0, 0, afr, bfr0);
    // ---- q1: read B(nh1); stage Bh1(t+1); certify Ah1(t) ----
    READ_B(bfr1, tb, 1);
    if (t + 1 < NT) { STAGE(Bb, 65536, t + 1, 1); VMC(12); } else { VMC(0); }
    BAR();
    LGKM0();
    MFMA_Q(0, 1, afr, bfr1);
    // ---- q2: read A(mh1); stage Ah1(t+1); certify Bh0(t+1) ----
    READ_A(afr, tb, 1);
    if (t + 1 < NT) { STAGE(Ab, 0, t + 1, 1); VMC(12); } else { VMC(0); }
    BAR();
    LGKM0();
    MFMA_Q(1, 1, afr, bfr1);
    // ---- q3: stage Bh0(t+2); certify Ah0(t+1); carry-read B(nh0)(t+1) ----
    if (t + 2 < NT)      { STAGE(Bb, 65536, t + 2, 0); VMC(12); }
    else if (t + 1 < NT) { VMC(8); }
    else                 { VMC(0); }
    BAR();
    LGKM0();
    MFMA_Q(1, 0, afr, bfr0);                  // consumes old bfr0
    if (t + 1 < NT) READ_B(bfr0, tb ^ 1, 0);  // overwrite-read t+1's nh0
  }

  // ---- epilogue: bias only -> raw bf16 Y -> LDS -> coalesced stores ----
  const int chunk = n0 >> 10;                 // block-uniform (BN=256 | 1024)
  const int hbase = (n0 & (H_DIM - 1)) + wc * 128;
  unsigned short* dst = (chunk == 0) ? wsZ : (chunk == 1) ? wsF : wsO;

  BAR();                                      // K-loop LDS fully done
  char* ep = lds + wid * 32768;               // 128 rows x 128 cols bf16
  float bv[8];
  #pragma unroll
  for (int n = 0; n < 8; ++n) bv[n] = bias[n0 + wc * 128 + n * 16 + lr];

  #pragma unroll
  for (int m = 0; m < 8; ++m)
    #pragma unroll
    for (int n = 0; n < 8; ++n)
      #pragma unroll
      for (int r = 0; r < 4; ++r) {
        int rowl = m * 16 + lg * 4 + r;       // 0..127
        *(unsigned short*)(ep + rowl * 256 + ((n * 16 + lr) << 1)) =
            f2bfbits(acc[m][n][r] + bv[n]);
      }

  // same-wave LDS readback: 4 rows/iter (16 lanes x 16B = 256B row)
  #pragma unroll
  for (int it = 0; it < 32; ++it) {
    int rl = it * 4 + (lane >> 4);
    short8 v = *(const short8*)(ep + rl * 256 + ((lane & 15) << 4));
    size_t grow = (size_t)(m0 + wr * 128 + rl);
    *(short8*)((char*)dst + (grow * H_DIM + hbase) * 2 + ((lane & 15) << 4)) = v;
  }
}

// ---------- blocked scan pass 1: scalar 1 ch/thread (R9 form) ----------
__global__ void scan_pass1(const __hip_bfloat16* __restrict__ F,
                           const __hip_bfloat16* __restrict__ Z,
                           float* __restrict__ chP, float* __restrict__ chA) {
  int t  = blockIdx.x * 256 + threadIdx.x;  // 0 .. NCHUNK*NCH-1
  int ch = t & (NCH - 1);
  int c  = t >> 14;
  size_t base = (size_t)c * CLEN * NCH + ch;
  float P = 1.f, A = 0.f;
  #pragma unroll 8
  for (int i = 0; i < CLEN; ++i) {
    float f = sig_fast(__bfloat162float(F[base + (size_t)i * NCH]));
    float z = tanh_fast(__bfloat162float(Z[base + (size_t)i * NCH]));
    A = fmaf(f, A, (1.f - f) * z);
    P *= f;
  }
  chP[t] = P;
  chA[t] = A;
}

// ---------- mid scan: sequential over 32 chunks per channel ----------
__global__ void scan_mid(const float* __restrict__ chP, const float* __restrict__ chA,
                         const float* __restrict__ hidden,
                         float* __restrict__ Cst, float* __restrict__ outLast) {
  int ch = blockIdx.x * 256 + threadIdx.x;  // 0..16383
  float c0 = hidden[ch];
  #pragma unroll
  for (int c = 0; c < NCHUNK; ++c) {
    Cst[c * NCH + ch] = c0;
    c0 = fmaf(chP[c * NCH + ch], c0, chA[c * NCH + ch]);
  }
  outLast[ch] = c0;  // C[S-1] output (fp32)
}

// ---------- pass 2: recompute within chunk; fuse Hout = sig(O)*C ----------
__global__ void scan_pass2(const __hip_bfloat16* __restrict__ F,
                           const __hip_bfloat16* __restrict__ Z,
                           const __hip_bfloat16* __restrict__ O,
                           const float* __restrict__ Cst,
                           float* __restrict__ out) {
  int t  = blockIdx.x * 256 + threadIdx.x;
  int ch = t & (NCH - 1);
  int c  = t >> 14;
  float C = Cst[c * NCH + ch];
  size_t base = (size_t)c * CLEN * NCH + ch;
  #pragma unroll 8
  for (int i = 0; i < CLEN; ++i) {
    size_t idx = base + (size_t)i * NCH;
    float f = sig_fast(__bfloat162float(F[idx]));
    float z = tanh_fast(__bfloat162float(Z[idx]));
    C = fmaf(f, C, (1.f - f) * z);
    out[idx] = sig_fast(__bfloat162float(O[idx])) * C;
  }
}

extern "C" void kernel_launch(void* const* d_in, const int* in_sizes, int n_in,
                              void* d_out, int out_size, void* d_ws, size_t ws_size,
                              hipStream_t stream) {
  const float* X      = (const float*)d_in[0];  // [S,B,D]
  const float* hidden = (const float*)d_in[1];  // [B,H]
  const float* W      = (const float*)d_in[2];  // [3H,D]
  const float* bias   = (const float*)d_in[3];  // [3H]
  float* out = (float*)d_out;                   // Hout [S,B,H] then C_last [1,B,H]

  char* ws = (char*)d_ws;
  __hip_bfloat16* Xb  = (__hip_bfloat16*)(ws);                 // 67,108,864
  __hip_bfloat16* Wb  = (__hip_bfloat16*)(ws + 67108864);      //  6,291,456
  unsigned short* wsZ = (unsigned short*)(ws + 73400320);      // 67,108,864 (raw Y bf16)
  unsigned short* wsF = (unsigned short*)(ws + 140509184);     // 67,108,864
  unsigned short* wsO = (unsigned short*)(ws + 207618048);     // 67,108,864
  float* chP = (float*)(ws + 274726912);                       //  2,097,152
  float* chA = (float*)(ws + 276824064);                       //  2,097,152
  float* Cst = (float*)(ws + 278921216);                       //  2,097,152

  // 1) convert X and W to bf16
  cvt_kernel<<<(M_TOT * K_TOT / 4 + 255) / 256, 256, 0, stream>>>(X, (unsigned short*)Xb, M_TOT * K_TOT / 4);
  cvt_kernel<<<(N_TOT * K_TOT / 4 + 255) / 256, 256, 0, stream>>>(W, (unsigned short*)Wb, N_TOT * K_TOT / 4);

  // 2) fused GEMM + bias (raw Y out; activations deferred to scans)
  gemm_act<<<NWG, 256, 0, stream>>>(Xb, Wb, bias, wsZ, wsF, wsO);

  // 3) blocked linear scan (scalar, full occupancy; activations fused here)
  scan_pass1<<<(NCHUNK * NCH) / 256, 256, 0, stream>>>(
      (const __hip_bfloat16*)wsF, (const __hip_bfloat16*)wsZ, chP, chA);
  scan_mid<<<NCH / 256, 256, 0, stream>>>(chP, chA, hidden, Cst,
                                          out + (size_t)M_TOT * H_DIM);
  scan_pass2<<<(NCHUNK * NCH) / 256, 256, 0, stream>>>(
      (const __hip_bfloat16*)wsF, (const __hip_bfloat16*)wsZ,
      (const __hip_bfloat16*)wsO, Cst, out);
}

// Round 13
// 333.420 us; speedup vs baseline: 1.0514x; 1.0514x over previous
//
#include <hip/hip_runtime.h>
#include <hip/hip_bf16.h>
#include <stdint.h>

#define S_LEN 2048
#define B_SZ  16
#define D_DIM 1024
#define H_DIM 1024
#define M_TOT (S_LEN * B_SZ)      // 32768
#define N_TOT (3 * H_DIM)         // 3072
#define K_TOT D_DIM               // 1024

// ---- GEMM geometry: 256x256 tile, BK=64, 8 waves (2Mx4N), 512 threads ----
#define BM 256
#define BN 256
#define BK 64
#define NT   (K_TOT / BK)         // 16 K-tiles
#define NTN  (N_TOT / BN)         // 12
#define NWG  ((M_TOT / BM) * NTN) // 1536 (divisible by 8 -> simple XCD swizzle)

#define NCHUNK 32
#define CLEN   64                 // NCHUNK*CLEN == S_LEN
#define NCH    (B_SZ * H_DIM)     // 16384 independent channels

typedef __attribute__((ext_vector_type(8))) short short8;
typedef __attribute__((ext_vector_type(4))) float f32x4;

// ---------- helpers ----------
__device__ __forceinline__ void gload_lds16(const void* g, void* l) {
  __builtin_amdgcn_global_load_lds((__attribute__((address_space(1))) void*)g,
                                   (__attribute__((address_space(3))) void*)l,
                                   16, 0, 0);
}

__device__ __forceinline__ unsigned short f2bfbits(float x) {
  union { __hip_bfloat16 h; unsigned short u; } cv;
  cv.h = __float2bfloat16(x);
  return cv.u;
}

// cheap native sigmoid/tanh (v_exp + v_rcp)
__device__ __forceinline__ float sig_fast(float y) {
  float e = __expf(y);
  return e * __builtin_amdgcn_rcpf(1.f + e);
}
__device__ __forceinline__ float tanh_fast(float y) {
  float e = __expf(2.f * y);
  return 2.f * (e * __builtin_amdgcn_rcpf(1.f + e)) - 1.f;
}

// ---------- fused fp32 -> bf16 conversion for X and W (one launch) ----------
__global__ void cvt2_kernel(const float* __restrict__ inX,
                            unsigned short* __restrict__ outX, int nX4,
                            const float* __restrict__ inW,
                            unsigned short* __restrict__ outW, int nW4) {
  int i = blockIdx.x * 256 + threadIdx.x;
  const float* in;
  unsigned short* out;
  int j;
  if (i < nX4) {
    in = inX; out = outX; j = i;
  } else if (i < nX4 + nW4) {
    in = inW; out = outW; j = i - nX4;
  } else {
    return;
  }
  float4 v = ((const float4*)in)[j];
  ushort4 o;
  o.x = f2bfbits(v.x); o.y = f2bfbits(v.y);
  o.z = f2bfbits(v.z); o.w = f2bfbits(v.w);
  ((ushort4*)out)[j] = o;
}

// ---------- GEMM: Y = Xb * Wb^T + bias -> raw bf16 Y chunks ----------
// (R9 configuration — best measured. 4 phases/K-tile, 1 barrier per phase:
// {new-half ds_reads; stage 1 half (2 gloads); vmcnt(6); BAR; lgkmcnt(0);
// 16 MFMA}. Rotation invariant: entering q0(t), in-flight = {Bh1(t), Ah1(t),
// Bh0(t+1)} = 6 loads; each phase's vmcnt(6) certifies exactly the half
// consumed next phase. Tails 2/0/0/4. Halves quadrant-aligned: A bit6, B bit5.
// LDS: A [2 buf][256 rows][128 B] @0, B same @65536 (128 KiB).
// slot^(row&7) involution swizzle (pre-swizzled global source + read-side).)
__global__ __launch_bounds__(512, 2) void gemm_act(
    const __hip_bfloat16* __restrict__ Xb,
    const __hip_bfloat16* __restrict__ Wb,
    const float* __restrict__ bias,
    unsigned short* __restrict__ wsZ,
    unsigned short* __restrict__ wsF,
    unsigned short* __restrict__ wsO) {
  __shared__ __align__(16) char lds[131072];

  int bid = blockIdx.x;
  int swz = (bid & 7) * (NWG >> 3) + (bid >> 3);   // XCD-aware, bijective
  int tm  = swz / NTN;
  int tn  = swz - tm * NTN;
  const int m0 = tm * BM;
  const int n0 = tn * BN;

  const int tid  = threadIdx.x;
  const int lane = tid & 63;
  const int wid  = tid >> 6;
  const int wr   = wid >> 2;        // 0..1 : wave row  (128 rows each)
  const int wc   = wid & 3;         // 0..3 : wave col  (64 cols each)
  const int lr   = lane & 15;
  const int lg   = lane >> 4;

  const char* Ab = (const char*)(Xb + (size_t)m0 * K_TOT);
  const char* Bb = (const char*)(Wb + (size_t)n0 * K_TOT);

  f32x4 acc[8][4];
  const f32x4 vz = {0.f, 0.f, 0.f, 0.f};
  #pragma unroll
  for (int m = 0; m < 8; ++m)
    #pragma unroll
    for (int n = 0; n < 4; ++n) acc[m][n] = vz;

  #define STAGE_A(tt, h)                                                      \
    {                                                                         \
      char* l = lds + (((tt) & 1) << 15);                                     \
      _Pragma("unroll")                                                       \
      for (int j = 0; j < 2; ++j) {                                           \
        int r = j * 128 + (h) * 64 + (tid >> 3);                              \
        gload_lds16(Ab + (size_t)r * (K_TOT * 2) + (size_t)(tt) * (BK * 2)    \
                       + (((tid & 7) ^ (r & 7)) << 4),                        \
                    l + r * 128 + ((tid & 7) << 4));                          \
      }                                                                       \
    }

  #define STAGE_B(tt, h)                                                      \
    {                                                                         \
      char* l = lds + 65536 + (((tt) & 1) << 15);                             \
      int u = tid >> 3;                                                       \
      _Pragma("unroll")                                                       \
      for (int j = 0; j < 2; ++j) {                                           \
        int r = j * 128 + (h) * 32 + (u & 31) + (u >> 5) * 64;                \
        gload_lds16(Bb + (size_t)r * (K_TOT * 2) + (size_t)(tt) * (BK * 2)    \
                       + (((tid & 7) ^ (r & 7)) << 4),                        \
                    l + r * 128 + ((tid & 7) << 4));                          \
      }                                                                       \
    }

  #define BAR()                                                               \
    { asm volatile("" ::: "memory");                                          \
      __builtin_amdgcn_s_barrier();                                           \
      asm volatile("" ::: "memory"); }

  #define LGKM0()                                                             \
    { asm volatile("s_waitcnt lgkmcnt(0)" ::: "memory");                      \
      __builtin_amdgcn_sched_barrier(0); }

  #define VMC(n)                                                              \
    { asm volatile("s_waitcnt vmcnt(" #n ")" ::: "memory");                   \
      __builtin_amdgcn_sched_barrier(0); }

  #define READ_A(dst, tb, mh)                                                 \
    _Pragma("unroll")                                                         \
    for (int mm = 0; mm < 4; ++mm)                                            \
      _Pragma("unroll")                                                       \
      for (int ks = 0; ks < 2; ++ks) {                                        \
        int row = wr * 128 + (mh) * 64 + mm * 16 + lr;                        \
        dst[mm][ks] = *(const short8*)(lds + ((tb) << 15) + row * 128 +       \
                                       ((((ks << 2) | lg) ^ (row & 7)) << 4));\
      }

  #define READ_B(dst, tb, nh)                                                 \
    _Pragma("unroll")                                                         \
    for (int nn = 0; nn < 2; ++nn)                                            \
      _Pragma("unroll")                                                       \
      for (int ks = 0; ks < 2; ++ks) {                                        \
        int row = wc * 64 + (nh) * 32 + nn * 16 + lr;                         \
        dst[nn][ks] = *(const short8*)(lds + 65536 + ((tb) << 15) +           \
                                       row * 128 +                            \
                                       ((((ks << 2) | lg) ^ (row & 7)) << 4));\
      }

  #define MFMA_Q(mh, nh, A, Bf)                                               \
    __builtin_amdgcn_s_setprio(1);                                            \
    _Pragma("unroll")                                                         \
    for (int ks = 0; ks < 2; ++ks)                                            \
      _Pragma("unroll")                                                       \
      for (int mm = 0; mm < 4; ++mm)                                          \
        _Pragma("unroll")                                                     \
        for (int nn = 0; nn < 2; ++nn)                                        \
          acc[(mh) * 4 + mm][(nh) * 2 + nn] =                                 \
              __builtin_amdgcn_mfma_f32_16x16x32_bf16(                        \
                  A[mm][ks], Bf[nn][ks], acc[(mh) * 4 + mm][(nh) * 2 + nn],   \
                  0, 0, 0);                                                   \
    __builtin_amdgcn_s_setprio(0);

  // prologue: certified {Ah0(0),Bh0(0)}; in-flight {Bh1(0),Ah1(0),Bh0(1)}
  STAGE_A(0, 0);
  STAGE_B(0, 0);
  STAGE_B(0, 1);
  STAGE_A(0, 1);
  STAGE_B(1, 0);
  VMC(6);
  BAR();

  short8 afr[4][2], bfr0[2][2], bfr1[2][2];
  READ_B(bfr0, 0, 0);   // carry-read Bh0(0) (certified)

  for (int t = 0; t < NT; ++t) {
    const int tb = t & 1;
    // ---- q0: read A(mh0); stage Ah0(t+1); certify Bh1(t) ----
    READ_A(afr, tb, 0);
    if (t + 1 < NT) { STAGE_A(t + 1, 0); VMC(6); } else { VMC(2); }
    BAR();
    LGKM0();
    MFMA_Q(0, 0, afr, bfr0);
    // ---- q1: read B(nh1); stage Bh1(t+1); certify Ah1(t) ----
    READ_B(bfr1, tb, 1);
    if (t + 1 < NT) { STAGE_B(t + 1, 1); VMC(6); } else { VMC(0); }
    BAR();
    LGKM0();
    MFMA_Q(0, 1, afr, bfr1);
    // ---- q2: read A(mh1); stage Ah1(t+1); certify Bh0(t+1) ----
    READ_A(afr, tb, 1);
    if (t + 1 < NT) { STAGE_A(t + 1, 1); VMC(6); } else { VMC(0); }
    BAR();
    LGKM0();
    MFMA_Q(1, 1, afr, bfr1);
    // ---- q3: stage Bh0(t+2); certify Ah0(t+1); carry-read B(nh0)(t+1) ----
    if (t + 2 < NT)      { STAGE_B(t + 2, 0); VMC(6); }
    else if (t + 1 < NT) { VMC(4); }
    else                 { VMC(0); }
    BAR();
    LGKM0();
    MFMA_Q(1, 0, afr, bfr0);                  // consumes old bfr0
    if (t + 1 < NT) READ_B(bfr0, tb ^ 1, 0);  // overwrite-read t+1's nh0
  }

  // ---- epilogue: bias only -> raw bf16 Y -> LDS -> coalesced stores ----
  const int chunk = n0 >> 10;                 // block-uniform (BN=256 | 1024)
  const int hbase = (n0 & (H_DIM - 1)) + wc * 64;
  unsigned short* dst = (chunk == 0) ? wsZ : (chunk == 1) ? wsF : wsO;

  BAR();                                      // K-loop LDS fully done
  char* ep = lds + wid * 16384;               // 128 rows x 64 cols bf16
  float bv[4];
  #pragma unroll
  for (int n = 0; n < 4; ++n) bv[n] = bias[n0 + wc * 64 + n * 16 + lr];

  #pragma unroll
  for (int m = 0; m < 8; ++m)
    #pragma unroll
    for (int n = 0; n < 4; ++n)
      #pragma unroll
      for (int r = 0; r < 4; ++r) {
        int rowl = m * 16 + lg * 4 + r;       // 0..127
        *(unsigned short*)(ep + rowl * 128 + ((n * 16 + lr) << 1)) =
            f2bfbits(acc[m][n][r] + bv[n]);
      }

  // same-wave LDS readback (compiler inserts lgkmcnt for the alias)
  #pragma unroll
  for (int it = 0; it < 16; ++it) {
    int rl = it * 8 + (lane >> 3);
    short8 v = *(const short8*)(ep + rl * 128 + ((lane & 7) << 4));
    size_t grow = (size_t)(m0 + wr * 128 + rl);
    *(short8*)((char*)dst + (grow * H_DIM + hbase) * 2 + ((lane & 7) << 4)) = v;
  }
}

// ---------- blocked scan pass 1: scalar 1 ch/thread, full occupancy ----------
__global__ void scan_pass1(const __hip_bfloat16* __restrict__ F,
                           const __hip_bfloat16* __restrict__ Z,
                           float* __restrict__ chP, float* __restrict__ chA) {
  int t  = blockIdx.x * 256 + threadIdx.x;  // 0 .. NCHUNK*NCH-1
  int ch = t & (NCH - 1);
  int c  = t >> 14;
  size_t base = (size_t)c * CLEN * NCH + ch;
  float P = 1.f, A = 0.f;
  #pragma unroll 8
  for (int i = 0; i < CLEN; ++i) {
    float f = sig_fast(__bfloat162float(F[base + (size_t)i * NCH]));
    float z = tanh_fast(__bfloat162float(Z[base + (size_t)i * NCH]));
    A = fmaf(f, A, (1.f - f) * z);
    P *= f;
  }
  chP[t] = P;
  chA[t] = A;
}

// ---------- mid scan: sequential over 32 chunks per channel ----------
__global__ void scan_mid(const float* __restrict__ chP, const float* __restrict__ chA,
                         const float* __restrict__ hidden,
                         float* __restrict__ Cst, float* __restrict__ outLast) {
  int ch = blockIdx.x * 256 + threadIdx.x;  // 0..16383
  float c0 = hidden[ch];
  #pragma unroll
  for (int c = 0; c < NCHUNK; ++c) {
    Cst[c * NCH + ch] = c0;
    c0 = fmaf(chP[c * NCH + ch], c0, chA[c * NCH + ch]);
  }
  outLast[ch] = c0;  // C[S-1] output (fp32)
}

// ---------- pass 2: recompute within chunk; fuse Hout = sig(O)*C ----------
__global__ void scan_pass2(const __hip_bfloat16* __restrict__ F,
                           const __hip_bfloat16* __restrict__ Z,
                           const __hip_bfloat16* __restrict__ O,
                           const float* __restrict__ Cst,
                           float* __restrict__ out) {
  int t  = blockIdx.x * 256 + threadIdx.x;
  int ch = t & (NCH - 1);
  int c  = t >> 14;
  float C = Cst[c * NCH + ch];
  size_t base = (size_t)c * CLEN * NCH + ch;
  #pragma unroll 8
  for (int i = 0; i < CLEN; ++i) {
    size_t idx = base + (size_t)i * NCH;
    float f = sig_fast(__bfloat162float(F[idx]));
    float z = tanh_fast(__bfloat162float(Z[idx]));
    C = fmaf(f, C, (1.f - f) * z);
    out[idx] = sig_fast(__bfloat162float(O[idx])) * C;
  }
}

extern "C" void kernel_launch(void* const* d_in, const int* in_sizes, int n_in,
                              void* d_out, int out_size, void* d_ws, size_t ws_size,
                              hipStream_t stream) {
  const float* X      = (const float*)d_in[0];  // [S,B,D]
  const float* hidden = (const float*)d_in[1];  // [B,H]
  const float* W      = (const float*)d_in[2];  // [3H,D]
  const float* bias   = (const float*)d_in[3];  // [3H]
  float* out = (float*)d_out;                   // Hout [S,B,H] then C_last [1,B,H]

  char* ws = (char*)d_ws;
  __hip_bfloat16* Xb  = (__hip_bfloat16*)(ws);                 // 67,108,864
  __hip_bfloat16* Wb  = (__hip_bfloat16*)(ws + 67108864);      //  6,291,456
  unsigned short* wsZ = (unsigned short*)(ws + 73400320);      // 67,108,864 (raw Y bf16)
  unsigned short* wsF = (unsigned short*)(ws + 140509184);     // 67,108,864
  unsigned short* wsO = (unsigned short*)(ws + 207618048);     // 67,108,864
  float* chP = (float*)(ws + 274726912);                       //  2,097,152
  float* chA = (float*)(ws + 276824064);                       //  2,097,152
  float* Cst = (float*)(ws + 278921216);                       //  2,097,152

  // 1) convert X and W to bf16 (single fused launch)
  const int nX4 = M_TOT * K_TOT / 4;   // 8388608
  const int nW4 = N_TOT * K_TOT / 4;   //  786432
  cvt2_kernel<<<(nX4 + nW4 + 255) / 256, 256, 0, stream>>>(
      X, (unsigned short*)Xb, nX4, W, (unsigned short*)Wb, nW4);

  // 2) fused GEMM + bias (raw Y out; activations deferred to scans)
  gemm_act<<<NWG, 512, 0, stream>>>(Xb, Wb, bias, wsZ, wsF, wsO);

  // 3) blocked linear scan (scalar, full occupancy; activations fused here)
  scan_pass1<<<(NCHUNK * NCH) / 256, 256, 0, stream>>>(
      (const __hip_bfloat16*)wsF, (const __hip_bfloat16*)wsZ, chP, chA);
  scan_mid<<<NCH / 256, 256, 0, stream>>>(chP, chA, hidden, Cst,
                                          out + (size_t)M_TOT * H_DIM);
  scan_pass2<<<(NCHUNK * NCH) / 256, 256, 0, stream>>>(
      (const __hip_bfloat16*)wsF, (const __hip_bfloat16*)wsZ,
      (const __hip_bfloat16*)wsO, Cst, out);
}

// Round 14
// 332.882 us; speedup vs baseline: 1.0531x; 1.0016x over previous
//
#include <hip/hip_runtime.h>
#include <hip/hip_bf16.h>
#include <stdint.h>

#define S_LEN 2048
#define B_SZ  16
#define D_DIM 1024
#define H_DIM 1024
#define M_TOT (S_LEN * B_SZ)      // 32768
#define N_TOT (3 * H_DIM)         // 3072
#define K_TOT D_DIM               // 1024

// ---- GEMM geometry: 256x256 tile, BK=64, 8 waves (2Mx4N), 512 threads ----
#define BM 256
#define BN 256
#define BK 64
#define NT   (K_TOT / BK)         // 16 K-tiles
#define NTN  (N_TOT / BN)         // 12
#define NWG  ((M_TOT / BM) * NTN) // 1536 (divisible by 8 -> simple XCD swizzle)

#define NCHUNK 32
#define CLEN   64                 // NCHUNK*CLEN == S_LEN
#define NCH    (B_SZ * H_DIM)     // 16384 independent channels

typedef __attribute__((ext_vector_type(8))) short short8;
typedef __attribute__((ext_vector_type(4))) float f32x4;

// ---------- helpers ----------
__device__ __forceinline__ void gload_lds16(const void* g, void* l) {
  __builtin_amdgcn_global_load_lds((__attribute__((address_space(1))) void*)g,
                                   (__attribute__((address_space(3))) void*)l,
                                   16, 0, 0);
}

__device__ __forceinline__ unsigned short f2bfbits(float x) {
  union { __hip_bfloat16 h; unsigned short u; } cv;
  cv.h = __float2bfloat16(x);
  return cv.u;
}

// cheap native sigmoid/tanh (v_exp + v_rcp)
__device__ __forceinline__ float sig_fast(float y) {
  float e = __expf(y);
  return e * __builtin_amdgcn_rcpf(1.f + e);
}
__device__ __forceinline__ float tanh_fast(float y) {
  float e = __expf(2.f * y);
  return 2.f * (e * __builtin_amdgcn_rcpf(1.f + e)) - 1.f;
}

// ---------- fused fp32 -> bf16 conversion for X and W (one launch) ----------
__global__ void cvt2_kernel(const float* __restrict__ inX,
                            unsigned short* __restrict__ outX, int nX4,
                            const float* __restrict__ inW,
                            unsigned short* __restrict__ outW, int nW4) {
  int i = blockIdx.x * 256 + threadIdx.x;
  const float* in;
  unsigned short* out;
  int j;
  if (i < nX4) {
    in = inX; out = outX; j = i;
  } else if (i < nX4 + nW4) {
    in = inW; out = outW; j = i - nX4;
  } else {
    return;
  }
  float4 v = ((const float4*)in)[j];
  ushort4 o;
  o.x = f2bfbits(v.x); o.y = f2bfbits(v.y);
  o.z = f2bfbits(v.z); o.w = f2bfbits(v.w);
  ((ushort4*)out)[j] = o;
}

// ---------- GEMM: Y = Xb * Wb^T + bias -> raw bf16 Y chunks ----------
// R13 schedule, minus the manual lgkmcnt(0) drains: ds_reads are compiler-
// visible loads, so the compiler emits fine-grained lgkmcnt(N) before each
// dependent MFMA (m97-verified) — first MFMA issues after its own operands
// land while later reads remain in flight. BAR/VMC structure unchanged:
// 4 phases/K-tile, rotating half-stage (A bit6 / B bit5 quadrant-aligned),
// counted vmcnt(6) per phase certifies exactly the half consumed next phase.
// LDS: A [2 buf][256 rows][128 B] @0, B same @65536 (128 KiB).
// slot^(row&7) involution swizzle (pre-swizzled global source + read-side).
__global__ __launch_bounds__(512, 2) void gemm_act(
    const __hip_bfloat16* __restrict__ Xb,
    const __hip_bfloat16* __restrict__ Wb,
    const float* __restrict__ bias,
    unsigned short* __restrict__ wsZ,
    unsigned short* __restrict__ wsF,
    unsigned short* __restrict__ wsO) {
  __shared__ __align__(16) char lds[131072];

  int bid = blockIdx.x;
  int swz = (bid & 7) * (NWG >> 3) + (bid >> 3);   // XCD-aware, bijective
  int tm  = swz / NTN;
  int tn  = swz - tm * NTN;
  const int m0 = tm * BM;
  const int n0 = tn * BN;

  const int tid  = threadIdx.x;
  const int lane = tid & 63;
  const int wid  = tid >> 6;
  const int wr   = wid >> 2;        // 0..1 : wave row  (128 rows each)
  const int wc   = wid & 3;         // 0..3 : wave col  (64 cols each)
  const int lr   = lane & 15;
  const int lg   = lane >> 4;

  const char* Ab = (const char*)(Xb + (size_t)m0 * K_TOT);
  const char* Bb = (const char*)(Wb + (size_t)n0 * K_TOT);

  f32x4 acc[8][4];
  const f32x4 vz = {0.f, 0.f, 0.f, 0.f};
  #pragma unroll
  for (int m = 0; m < 8; ++m)
    #pragma unroll
    for (int n = 0; n < 4; ++n) acc[m][n] = vz;

  #define STAGE_A(tt, h)                                                      \
    {                                                                         \
      char* l = lds + (((tt) & 1) << 15);                                     \
      _Pragma("unroll")                                                       \
      for (int j = 0; j < 2; ++j) {                                           \
        int r = j * 128 + (h) * 64 + (tid >> 3);                              \
        gload_lds16(Ab + (size_t)r * (K_TOT * 2) + (size_t)(tt) * (BK * 2)    \
                       + (((tid & 7) ^ (r & 7)) << 4),                        \
                    l + r * 128 + ((tid & 7) << 4));                          \
      }                                                                       \
    }

  #define STAGE_B(tt, h)                                                      \
    {                                                                         \
      char* l = lds + 65536 + (((tt) & 1) << 15);                             \
      int u = tid >> 3;                                                       \
      _Pragma("unroll")                                                       \
      for (int j = 0; j < 2; ++j) {                                           \
        int r = j * 128 + (h) * 32 + (u & 31) + (u >> 5) * 64;                \
        gload_lds16(Bb + (size_t)r * (K_TOT * 2) + (size_t)(tt) * (BK * 2)    \
                       + (((tid & 7) ^ (r & 7)) << 4),                        \
                    l + r * 128 + ((tid & 7) << 4));                          \
      }                                                                       \
    }

  #define BAR()                                                               \
    { asm volatile("" ::: "memory");                                          \
      __builtin_amdgcn_s_barrier();                                           \
      asm volatile("" ::: "memory"); }

  #define VMC(n)                                                              \
    { asm volatile("s_waitcnt vmcnt(" #n ")" ::: "memory");                   \
      __builtin_amdgcn_sched_barrier(0); }

  #define READ_A(dst, tb, mh)                                                 \
    _Pragma("unroll")                                                         \
    for (int mm = 0; mm < 4; ++mm)                                            \
      _Pragma("unroll")                                                       \
      for (int ks = 0; ks < 2; ++ks) {                                        \
        int row = wr * 128 + (mh) * 64 + mm * 16 + lr;                        \
        dst[mm][ks] = *(const short8*)(lds + ((tb) << 15) + row * 128 +       \
                                       ((((ks << 2) | lg) ^ (row & 7)) << 4));\
      }

  #define READ_B(dst, tb, nh)                                                 \
    _Pragma("unroll")                                                         \
    for (int nn = 0; nn < 2; ++nn)                                            \
      _Pragma("unroll")                                                       \
      for (int ks = 0; ks < 2; ++ks) {                                        \
        int row = wc * 64 + (nh) * 32 + nn * 16 + lr;                         \
        dst[nn][ks] = *(const short8*)(lds + 65536 + ((tb) << 15) +           \
                                       row * 128 +                            \
                                       ((((ks << 2) | lg) ^ (row & 7)) << 4));\
      }

  #define MFMA_Q(mh, nh, A, Bf)                                               \
    __builtin_amdgcn_s_setprio(1);                                            \
    _Pragma("unroll")                                                         \
    for (int ks = 0; ks < 2; ++ks)                                            \
      _Pragma("unroll")                                                       \
      for (int mm = 0; mm < 4; ++mm)                                          \
        _Pragma("unroll")                                                     \
        for (int nn = 0; nn < 2; ++nn)                                        \
          acc[(mh) * 4 + mm][(nh) * 2 + nn] =                                 \
              __builtin_amdgcn_mfma_f32_16x16x32_bf16(                        \
                  A[mm][ks], Bf[nn][ks], acc[(mh) * 4 + mm][(nh) * 2 + nn],   \
                  0, 0, 0);                                                   \
    __builtin_amdgcn_s_setprio(0);

  // prologue: certified {Ah0(0),Bh0(0)}; in-flight {Bh1(0),Ah1(0),Bh0(1)}
  STAGE_A(0, 0);
  STAGE_B(0, 0);
  STAGE_B(0, 1);
  STAGE_A(0, 1);
  STAGE_B(1, 0);
  VMC(6);
  BAR();

  short8 afr[4][2], bfr0[2][2], bfr1[2][2];
  READ_B(bfr0, 0, 0);   // carry-read Bh0(0) (certified)

  for (int t = 0; t < NT; ++t) {
    const int tb = t & 1;
    // ---- q0: read A(mh0); stage Ah0(t+1); certify Bh1(t) ----
    READ_A(afr, tb, 0);
    if (t + 1 < NT) { STAGE_A(t + 1, 0); VMC(6); } else { VMC(2); }
    BAR();
    MFMA_Q(0, 0, afr, bfr0);      // compiler emits fine-grained lgkmcnt
    // ---- q1: read B(nh1); stage Bh1(t+1); certify Ah1(t) ----
    READ_B(bfr1, tb, 1);
    if (t + 1 < NT) { STAGE_B(t + 1, 1); VMC(6); } else { VMC(0); }
    BAR();
    MFMA_Q(0, 1, afr, bfr1);
    // ---- q2: read A(mh1); stage Ah1(t+1); certify Bh0(t+1) ----
    READ_A(afr, tb, 1);
    if (t + 1 < NT) { STAGE_A(t + 1, 1); VMC(6); } else { VMC(0); }
    BAR();
    MFMA_Q(1, 1, afr, bfr1);
    // ---- q3: stage Bh0(t+2); certify Ah0(t+1); carry-read B(nh0)(t+1) ----
    if (t + 2 < NT)      { STAGE_B(t + 2, 0); VMC(6); }
    else if (t + 1 < NT) { VMC(4); }
    else                 { VMC(0); }
    BAR();
    MFMA_Q(1, 0, afr, bfr0);                  // consumes old bfr0
    if (t + 1 < NT) READ_B(bfr0, tb ^ 1, 0);  // overwrite-read t+1's nh0
  }

  // ---- epilogue: bias only -> raw bf16 Y -> LDS -> coalesced stores ----
  const int chunk = n0 >> 10;                 // block-uniform (BN=256 | 1024)
  const int hbase = (n0 & (H_DIM - 1)) + wc * 64;
  unsigned short* dst = (chunk == 0) ? wsZ : (chunk == 1) ? wsF : wsO;

  BAR();                                      // K-loop LDS fully done
  char* ep = lds + wid * 16384;               // 128 rows x 64 cols bf16
  float bv[4];
  #pragma unroll
  for (int n = 0; n < 4; ++n) bv[n] = bias[n0 + wc * 64 + n * 16 + lr];

  #pragma unroll
  for (int m = 0; m < 8; ++m)
    #pragma unroll
    for (int n = 0; n < 4; ++n)
      #pragma unroll
      for (int r = 0; r < 4; ++r) {
        int rowl = m * 16 + lg * 4 + r;       // 0..127
        *(unsigned short*)(ep + rowl * 128 + ((n * 16 + lr) << 1)) =
            f2bfbits(acc[m][n][r] + bv[n]);
      }

  // same-wave LDS readback (compiler inserts lgkmcnt for the alias)
  #pragma unroll
  for (int it = 0; it < 16; ++it) {
    int rl = it * 8 + (lane >> 3);
    short8 v = *(const short8*)(ep + rl * 128 + ((lane & 7) << 4));
    size_t grow = (size_t)(m0 + wr * 128 + rl);
    *(short8*)((char*)dst + (grow * H_DIM + hbase) * 2 + ((lane & 7) << 4)) = v;
  }
}

// ---------- blocked scan pass 1: scalar 1 ch/thread, full occupancy ----------
__global__ void scan_pass1(const __hip_bfloat16* __restrict__ F,
                           const __hip_bfloat16* __restrict__ Z,
                           float* __restrict__ chP, float* __restrict__ chA) {
  int t  = blockIdx.x * 256 + threadIdx.x;  // 0 .. NCHUNK*NCH-1
  int ch = t & (NCH - 1);
  int c  = t >> 14;
  size_t base = (size_t)c * CLEN * NCH + ch;
  float P = 1.f, A = 0.f;
  #pragma unroll 8
  for (int i = 0; i < CLEN; ++i) {
    float f = sig_fast(__bfloat162float(F[base + (size_t)i * NCH]));
    float z = tanh_fast(__bfloat162float(Z[base + (size_t)i * NCH]));
    A = fmaf(f, A, (1.f - f) * z);
    P *= f;
  }
  chP[t] = P;
  chA[t] = A;
}

// ---------- mid scan: sequential over 32 chunks per channel ----------
__global__ void scan_mid(const float* __restrict__ chP, const float* __restrict__ chA,
                         const float* __restrict__ hidden,
                         float* __restrict__ Cst, float* __restrict__ outLast) {
  int ch = blockIdx.x * 256 + threadIdx.x;  // 0..16383
  float c0 = hidden[ch];
  #pragma unroll
  for (int c = 0; c < NCHUNK; ++c) {
    Cst[c * NCH + ch] = c0;
    c0 = fmaf(chP[c * NCH + ch], c0, chA[c * NCH + ch]);
  }
  outLast[ch] = c0;  // C[S-1] output (fp32)
}

// ---------- pass 2: recompute within chunk; fuse Hout = sig(O)*C ----------
__global__ void scan_pass2(const __hip_bfloat16* __restrict__ F,
                           const __hip_bfloat16* __restrict__ Z,
                           const __hip_bfloat16* __restrict__ O,
                           const float* __restrict__ Cst,
                           float* __restrict__ out) {
  int t  = blockIdx.x * 256 + threadIdx.x;
  int ch = t & (NCH - 1);
  int c  = t >> 14;
  float C = Cst[c * NCH + ch];
  size_t base = (size_t)c * CLEN * NCH + ch;
  #pragma unroll 8
  for (int i = 0; i < CLEN; ++i) {
    size_t idx = base + (size_t)i * NCH;
    float f = sig_fast(__bfloat162float(F[idx]));
    float z = tanh_fast(__bfloat162float(Z[idx]));
    C = fmaf(f, C, (1.f - f) * z);
    out[idx] = sig_fast(__bfloat162float(O[idx])) * C;
  }
}

extern "C" void kernel_launch(void* const* d_in, const int* in_sizes, int n_in,
                              void* d_out, int out_size, void* d_ws, size_t ws_size,
                              hipStream_t stream) {
  const float* X      = (const float*)d_in[0];  // [S,B,D]
  const float* hidden = (const float*)d_in[1];  // [B,H]
  const float* W      = (const float*)d_in[2];  // [3H,D]
  const float* bias   = (const float*)d_in[3];  // [3H]
  float* out = (float*)d_out;                   // Hout [S,B,H] then C_last [1,B,H]

  char* ws = (char*)d_ws;
  __hip_bfloat16* Xb  = (__hip_bfloat16*)(ws);                 // 67,108,864
  __hip_bfloat16* Wb  = (__hip_bfloat16*)(ws + 67108864);      //  6,291,456
  unsigned short* wsZ = (unsigned short*)(ws + 73400320);      // 67,108,864 (raw Y bf16)
  unsigned short* wsF = (unsigned short*)(ws + 140509184);     // 67,108,864
  unsigned short* wsO = (unsigned short*)(ws + 207618048);     // 67,108,864
  float* chP = (float*)(ws + 274726912);                       //  2,097,152
  float* chA = (float*)(ws + 276824064);                       //  2,097,152
  float* Cst = (float*)(ws + 278921216);                       //  2,097,152

  // 1) convert X and W to bf16 (single fused launch)
  const int nX4 = M_TOT * K_TOT / 4;   // 8388608
  const int nW4 = N_TOT * K_TOT / 4;   //  786432
  cvt2_kernel<<<(nX4 + nW4 + 255) / 256, 256, 0, stream>>>(
      X, (unsigned short*)Xb, nX4, W, (unsigned short*)Wb, nW4);

  // 2) fused GEMM + bias (raw Y out; activations deferred to scans)
  gemm_act<<<NWG, 512, 0, stream>>>(Xb, Wb, bias, wsZ, wsF, wsO);

  // 3) blocked linear scan (scalar, full occupancy; activations fused here)
  scan_pass1<<<(NCHUNK * NCH) / 256, 256, 0, stream>>>(
      (const __hip_bfloat16*)wsF, (const __hip_bfloat16*)wsZ, chP, chA);
  scan_mid<<<NCH / 256, 256, 0, stream>>>(chP, chA, hidden, Cst,
                                          out + (size_t)M_TOT * H_DIM);
  scan_pass2<<<(NCHUNK * NCH) / 256, 256, 0, stream>>>(
      (const __hip_bfloat16*)wsF, (const __hip_bfloat16*)wsZ,
      (const __hip_bfloat16*)wsO, Cst, out);
}

// Round 15
// 330.611 us; speedup vs baseline: 1.0603x; 1.0069x over previous
//
#include <hip/hip_runtime.h>
#include <hip/hip_bf16.h>
#include <stdint.h>

#define S_LEN 2048
#define B_SZ  16
#define D_DIM 1024
#define H_DIM 1024
#define M_TOT (S_LEN * B_SZ)      // 32768
#define N_TOT (3 * H_DIM)         // 3072
#define K_TOT D_DIM               // 1024

// ---- GEMM geometry: 256x256 tile, BK=64, 8 waves (2Mx4N), 512 threads ----
#define BM 256
#define BN 256
#define BK 64
#define NT   (K_TOT / BK)         // 16 K-tiles
#define NTN  (N_TOT / BN)         // 12
#define NWG  ((M_TOT / BM) * NTN) // 1536 (divisible by 8 -> simple XCD swizzle)

#define NCHUNK 32
#define CLEN   64                 // NCHUNK*CLEN == S_LEN
#define NCH    (B_SZ * H_DIM)     // 16384 independent channels

typedef __attribute__((ext_vector_type(8))) short short8;
typedef __attribute__((ext_vector_type(4))) float f32x4;

// ---------- helpers ----------
__device__ __forceinline__ void gload_lds16(const void* g, void* l) {
  __builtin_amdgcn_global_load_lds((__attribute__((address_space(1))) void*)g,
                                   (__attribute__((address_space(3))) void*)l,
                                   16, 0, 0);
}

__device__ __forceinline__ unsigned short f2bfbits(float x) {
  union { __hip_bfloat16 h; unsigned short u; } cv;
  cv.h = __float2bfloat16(x);
  return cv.u;
}

// cheap native sigmoid/tanh (v_exp + v_rcp)
__device__ __forceinline__ float sig_fast(float y) {
  float e = __expf(y);
  return e * __builtin_amdgcn_rcpf(1.f + e);
}
__device__ __forceinline__ float tanh_fast(float y) {
  float e = __expf(2.f * y);
  return 2.f * (e * __builtin_amdgcn_rcpf(1.f + e)) - 1.f;
}

// ---------- fused fp32 -> bf16 conversion for X and W (one launch) ----------
__global__ void cvt2_kernel(const float* __restrict__ inX,
                            unsigned short* __restrict__ outX, int nX4,
                            const float* __restrict__ inW,
                            unsigned short* __restrict__ outW, int nW4) {
  int i = blockIdx.x * 256 + threadIdx.x;
  const float* in;
  unsigned short* out;
  int j;
  if (i < nX4) {
    in = inX; out = outX; j = i;
  } else if (i < nX4 + nW4) {
    in = inW; out = outW; j = i - nX4;
  } else {
    return;
  }
  float4 v = ((const float4*)in)[j];
  ushort4 o;
  o.x = f2bfbits(v.x); o.y = f2bfbits(v.y);
  o.z = f2bfbits(v.z); o.w = f2bfbits(v.w);
  ((ushort4*)out)[j] = o;
}

// ---------- GEMM: Y = Xb * Wb^T + bias -> raw bf16 Y chunks ----------
// R13 schedule with m201-cadence vmcnt: counted waits only at q1 (vmcnt 6)
// and q3 (vmcnt 4) — twice per K-tile, never 0 in steady state — and no
// sched_barrier after them (certified consumers are ds_reads, ordered by the
// "memory" clobber). Cert coverage (stages q0:Ah0(t+1) q1:Bh1(t+1)
// q2:Ah1(t+1) q3:Bh0(t+2)): q1's vmcnt(6) certifies Ah1(t) for q2;
// q3's vmcnt(4) certifies {Bh0,Ah0,Bh1}(t+1) for the carry-read and all of
// tile t+1's pre-cert reads. Tails: q3(NT-2)=2, q1(NT-1)=0.
// LDS: A [2 buf][256 rows][128 B] @0, B same @65536 (128 KiB).
// slot^(row&7) involution swizzle (pre-swizzled global source + read-side).
__global__ __launch_bounds__(512, 2) void gemm_act(
    const __hip_bfloat16* __restrict__ Xb,
    const __hip_bfloat16* __restrict__ Wb,
    const float* __restrict__ bias,
    unsigned short* __restrict__ wsZ,
    unsigned short* __restrict__ wsF,
    unsigned short* __restrict__ wsO) {
  __shared__ __align__(16) char lds[131072];

  int bid = blockIdx.x;
  int swz = (bid & 7) * (NWG >> 3) + (bid >> 3);   // XCD-aware, bijective
  int tm  = swz / NTN;
  int tn  = swz - tm * NTN;
  const int m0 = tm * BM;
  const int n0 = tn * BN;

  const int tid  = threadIdx.x;
  const int lane = tid & 63;
  const int wid  = tid >> 6;
  const int wr   = wid >> 2;        // 0..1 : wave row  (128 rows each)
  const int wc   = wid & 3;         // 0..3 : wave col  (64 cols each)
  const int lr   = lane & 15;
  const int lg   = lane >> 4;

  const char* Ab = (const char*)(Xb + (size_t)m0 * K_TOT);
  const char* Bb = (const char*)(Wb + (size_t)n0 * K_TOT);

  f32x4 acc[8][4];
  const f32x4 vz = {0.f, 0.f, 0.f, 0.f};
  #pragma unroll
  for (int m = 0; m < 8; ++m)
    #pragma unroll
    for (int n = 0; n < 4; ++n) acc[m][n] = vz;

  #define STAGE_A(tt, h)                                                      \
    {                                                                         \
      char* l = lds + (((tt) & 1) << 15);                                     \
      _Pragma("unroll")                                                       \
      for (int j = 0; j < 2; ++j) {                                           \
        int r = j * 128 + (h) * 64 + (tid >> 3);                              \
        gload_lds16(Ab + (size_t)r * (K_TOT * 2) + (size_t)(tt) * (BK * 2)    \
                       + (((tid & 7) ^ (r & 7)) << 4),                        \
                    l + r * 128 + ((tid & 7) << 4));                          \
      }                                                                       \
    }

  #define STAGE_B(tt, h)                                                      \
    {                                                                         \
      char* l = lds + 65536 + (((tt) & 1) << 15);                             \
      int u = tid >> 3;                                                       \
      _Pragma("unroll")                                                       \
      for (int j = 0; j < 2; ++j) {                                           \
        int r = j * 128 + (h) * 32 + (u & 31) + (u >> 5) * 64;                \
        gload_lds16(Bb + (size_t)r * (K_TOT * 2) + (size_t)(tt) * (BK * 2)    \
                       + (((tid & 7) ^ (r & 7)) << 4),                        \
                    l + r * 128 + ((tid & 7) << 4));                          \
      }                                                                       \
    }

  #define BAR()                                                               \
    { asm volatile("" ::: "memory");                                          \
      __builtin_amdgcn_s_barrier();                                           \
      asm volatile("" ::: "memory"); }

  #define VMC(n)                                                              \
    asm volatile("s_waitcnt vmcnt(" #n ")" ::: "memory");

  #define READ_A(dst, tb, mh)                                                 \
    _Pragma("unroll")                                                         \
    for (int mm = 0; mm < 4; ++mm)                                            \
      _Pragma("unroll")                                                       \
      for (int ks = 0; ks < 2; ++ks) {                                        \
        int row = wr * 128 + (mh) * 64 + mm * 16 + lr;                        \
        dst[mm][ks] = *(const short8*)(lds + ((tb) << 15) + row * 128 +       \
                                       ((((ks << 2) | lg) ^ (row & 7)) << 4));\
      }

  #define READ_B(dst, tb, nh)                                                 \
    _Pragma("unroll")                                                         \
    for (int nn = 0; nn < 2; ++nn)                                            \
      _Pragma("unroll")                                                       \
      for (int ks = 0; ks < 2; ++ks) {                                        \
        int row = wc * 64 + (nh) * 32 + nn * 16 + lr;                         \
        dst[nn][ks] = *(const short8*)(lds + 65536 + ((tb) << 15) +           \
                                       row * 128 +                            \
                                       ((((ks << 2) | lg) ^ (row & 7)) << 4));\
      }

  #define MFMA_Q(mh, nh, A, Bf)                                               \
    __builtin_amdgcn_s_setprio(1);                                            \
    _Pragma("unroll")                                                         \
    for (int ks = 0; ks < 2; ++ks)                                            \
      _Pragma("unroll")                                                       \
      for (int mm = 0; mm < 4; ++mm)                                          \
        _Pragma("unroll")                                                     \
        for (int nn = 0; nn < 2; ++nn)                                        \
          acc[(mh) * 4 + mm][(nh) * 2 + nn] =                                 \
              __builtin_amdgcn_mfma_f32_16x16x32_bf16(                        \
                  A[mm][ks], Bf[nn][ks], acc[(mh) * 4 + mm][(nh) * 2 + nn],   \
                  0, 0, 0);                                                   \
    __builtin_amdgcn_s_setprio(0);

  // prologue: certify {Ah0(0),Bh0(0),Bh1(0)}; in-flight {Ah1(0),Bh0(1)} = 4
  STAGE_A(0, 0);
  STAGE_B(0, 0);
  STAGE_B(0, 1);
  STAGE_A(0, 1);
  STAGE_B(1, 0);
  VMC(4);
  BAR();

  short8 afr[4][2], bfr0[2][2], bfr1[2][2];
  READ_B(bfr0, 0, 0);   // carry-read Bh0(0) (certified)

  for (int t = 0; t < NT; ++t) {
    const int tb = t & 1;
    // ---- q0: read A(mh0) [cert by q3(t-1)]; stage Ah0(t+1); no wait ----
    READ_A(afr, tb, 0);
    if (t + 1 < NT) STAGE_A(t + 1, 0);
    BAR();
    MFMA_Q(0, 0, afr, bfr0);      // compiler emits fine-grained lgkmcnt
    // ---- q1: read B(nh1) [cert by q3(t-1)]; stage Bh1(t+1); vmcnt(6) ----
    READ_B(bfr1, tb, 1);
    if (t + 1 < NT) { STAGE_B(t + 1, 1); VMC(6); } else { VMC(0); }
    BAR();                        // certifies Ah1(t) block-wide
    MFMA_Q(0, 1, afr, bfr1);
    // ---- q2: read A(mh1) [cert by q1(t)]; stage Ah1(t+1); no wait ----
    READ_A(afr, tb, 1);
    if (t + 1 < NT) STAGE_A(t + 1, 1);
    BAR();
    MFMA_Q(1, 1, afr, bfr1);
    // ---- q3: stage Bh0(t+2); vmcnt(4) certifies {Bh0,Ah0,Bh1}(t+1) ----
    if (t + 2 < NT)      { STAGE_B(t + 2, 0); VMC(4); }
    else if (t == NT - 2) { VMC(2); }
    BAR();                        // collective cert for tile t+1
    MFMA_Q(1, 0, afr, bfr0);      // consumes old bfr0
    if (t + 1 < NT) READ_B(bfr0, tb ^ 1, 0);  // carry-read t+1's nh0
  }

  // ---- epilogue: bias only -> raw bf16 Y -> LDS -> coalesced stores ----
  const int chunk = n0 >> 10;                 // block-uniform (BN=256 | 1024)
  const int hbase = (n0 & (H_DIM - 1)) + wc * 64;
  unsigned short* dst = (chunk == 0) ? wsZ : (chunk == 1) ? wsF : wsO;

  BAR();                                      // K-loop LDS fully done
  char* ep = lds + wid * 16384;               // 128 rows x 64 cols bf16
  float bv[4];
  #pragma unroll
  for (int n = 0; n < 4; ++n) bv[n] = bias[n0 + wc * 64 + n * 16 + lr];

  #pragma unroll
  for (int m = 0; m < 8; ++m)
    #pragma unroll
    for (int n = 0; n < 4; ++n)
      #pragma unroll
      for (int r = 0; r < 4; ++r) {
        int rowl = m * 16 + lg * 4 + r;       // 0..127
        *(unsigned short*)(ep + rowl * 128 + ((n * 16 + lr) << 1)) =
            f2bfbits(acc[m][n][r] + bv[n]);
      }

  // same-wave LDS readback (compiler inserts lgkmcnt for the alias)
  #pragma unroll
  for (int it = 0; it < 16; ++it) {
    int rl = it * 8 + (lane >> 3);
    short8 v = *(const short8*)(ep + rl * 128 + ((lane & 7) << 4));
    size_t grow = (size_t)(m0 + wr * 128 + rl);
    *(short8*)((char*)dst + (grow * H_DIM + hbase) * 2 + ((lane & 7) << 4)) = v;
  }
}

// ---------- blocked scan pass 1: scalar 1 ch/thread, full occupancy ----------
__global__ void scan_pass1(const __hip_bfloat16* __restrict__ F,
                           const __hip_bfloat16* __restrict__ Z,
                           float* __restrict__ chP, float* __restrict__ chA) {
  int t  = blockIdx.x * 256 + threadIdx.x;  // 0 .. NCHUNK*NCH-1
  int ch = t & (NCH - 1);
  int c  = t >> 14;
  size_t base = (size_t)c * CLEN * NCH + ch;
  float P = 1.f, A = 0.f;
  #pragma unroll 8
  for (int i = 0; i < CLEN; ++i) {
    float f = sig_fast(__bfloat162float(F[base + (size_t)i * NCH]));
    float z = tanh_fast(__bfloat162float(Z[base + (size_t)i * NCH]));
    A = fmaf(f, A, (1.f - f) * z);
    P *= f;
  }
  chP[t] = P;
  chA[t] = A;
}

// ---------- mid scan: sequential over 32 chunks per channel ----------
__global__ void scan_mid(const float* __restrict__ chP, const float* __restrict__ chA,
                         const float* __restrict__ hidden,
                         float* __restrict__ Cst, float* __restrict__ outLast) {
  int ch = blockIdx.x * 256 + threadIdx.x;  // 0..16383
  float c0 = hidden[ch];
  #pragma unroll
  for (int c = 0; c < NCHUNK; ++c) {
    Cst[c * NCH + ch] = c0;
    c0 = fmaf(chP[c * NCH + ch], c0, chA[c * NCH + ch]);
  }
  outLast[ch] = c0;  // C[S-1] output (fp32)
}

// ---------- pass 2: recompute within chunk; fuse Hout = sig(O)*C ----------
__global__ void scan_pass2(const __hip_bfloat16* __restrict__ F,
                           const __hip_bfloat16* __restrict__ Z,
                           const __hip_bfloat16* __restrict__ O,
                           const float* __restrict__ Cst,
                           float* __restrict__ out) {
  int t  = blockIdx.x * 256 + threadIdx.x;
  int ch = t & (NCH - 1);
  int c  = t >> 14;
  float C = Cst[c * NCH + ch];
  size_t base = (size_t)c * CLEN * NCH + ch;
  #pragma unroll 8
  for (int i = 0; i < CLEN; ++i) {
    size_t idx = base + (size_t)i * NCH;
    float f = sig_fast(__bfloat162float(F[idx]));
    float z = tanh_fast(__bfloat162float(Z[idx]));
    C = fmaf(f, C, (1.f - f) * z);
    out[idx] = sig_fast(__bfloat162float(O[idx])) * C;
  }
}

extern "C" void kernel_launch(void* const* d_in, const int* in_sizes, int n_in,
                              void* d_out, int out_size, void* d_ws, size_t ws_size,
                              hipStream_t stream) {
  const float* X      = (const float*)d_in[0];  // [S,B,D]
  const float* hidden = (const float*)d_in[1];  // [B,H]
  const float* W      = (const float*)d_in[2];  // [3H,D]
  const float* bias   = (const float*)d_in[3];  // [3H]
  float* out = (float*)d_out;                   // Hout [S,B,H] then C_last [1,B,H]

  char* ws = (char*)d_ws;
  __hip_bfloat16* Xb  = (__hip_bfloat16*)(ws);                 // 67,108,864
  __hip_bfloat16* Wb  = (__hip_bfloat16*)(ws + 67108864);      //  6,291,456
  unsigned short* wsZ = (unsigned short*)(ws + 73400320);      // 67,108,864 (raw Y bf16)
  unsigned short* wsF = (unsigned short*)(ws + 140509184);     // 67,108,864
  unsigned short* wsO = (unsigned short*)(ws + 207618048);     // 67,108,864
  float* chP = (float*)(ws + 274726912);                       //  2,097,152
  float* chA = (float*)(ws + 276824064);                       //  2,097,152
  float* Cst = (float*)(ws + 278921216);                       //  2,097,152

  // 1) convert X and W to bf16 (single fused launch)
  const int nX4 = M_TOT * K_TOT / 4;   // 8388608
  const int nW4 = N_TOT * K_TOT / 4;   //  786432
  cvt2_kernel<<<(nX4 + nW4 + 255) / 256, 256, 0, stream>>>(
      X, (unsigned short*)Xb, nX4, W, (unsigned short*)Wb, nW4);

  // 2) fused GEMM + bias (raw Y out; activations deferred to scans)
  gemm_act<<<NWG, 512, 0, stream>>>(Xb, Wb, bias, wsZ, wsF, wsO);

  // 3) blocked linear scan (scalar, full occupancy; activations fused here)
  scan_pass1<<<(NCHUNK * NCH) / 256, 256, 0, stream>>>(
      (const __hip_bfloat16*)wsF, (const __hip_bfloat16*)wsZ, chP, chA);
  scan_mid<<<NCH / 256, 256, 0, stream>>>(chP, chA, hidden, Cst,
                                          out + (size_t)M_TOT * H_DIM);
  scan_pass2<<<(NCHUNK * NCH) / 256, 256, 0, stream>>>(
      (const __hip_bfloat16*)wsF, (const __hip_bfloat16*)wsZ,
      (const __hip_bfloat16*)wsO, Cst, out);
}